// Round 10
// baseline (415.906 us; speedup 1.0000x reference)
//
#include <hip/hip_runtime.h>
#include <hip/hip_bf16.h>
#include <stdint.h>

// ---------------------------------------------------------------------------
// LSTM2: 3 stacked single-step LSTM cells (h0=c0=0 => f-gate dead) + fc1+fc2.
// B=8192, I=128, T=21 -> M = 172032 rows.
// R1: XOR-swizzle LDS (bank conflicts -> 0, verified).
// R2: global_load_lds width=16 staging.
// R3: row-fastest grid; cheap activation (8 -> 5 trans ops/h).
// R4: FAILED - (256,4) spilled acc -> WRITE 608MB. (256,3) also spills (R2:
//     181MB). (256,2) is the no-spill point.
// R5: 406us. L2-gemm 112us = 604TF = 24% peak == MfmaUtil. Post-mortem:
//     reg-staged(R0) == gload_lds(R5) == 112-113us -> 2-barrier-per-kk
//     structure ceiling; ~60% of round time is the per-kk vmcnt(0)+barrier
//     drain at 2 waves/SIMD.
// R8: 2-phase counted pipeline (T3 minimum): BK=32 double-buffer (40KB total,
//     keeps residency), stage(t+1) BEFORE compute(t), ONE barrier per tile.
//     Swizzle for 4-slot rows: slot ^= (row>>1)&3 (2-way max = free).
//     + float4 transpose loads / uint stores; converts merged to 1 launch.
// ---------------------------------------------------------------------------

typedef __attribute__((ext_vector_type(8))) short bf16x8;
typedef __attribute__((ext_vector_type(4))) float f32x4;

#define M_ROWS 172032
#define BATCH  8192

__device__ __forceinline__ float bf2f(unsigned short u) {
    union { unsigned int i; float f; } v; v.i = ((unsigned int)u) << 16; return v.f;
}
__device__ __forceinline__ unsigned short f2bf(float f) {
    union { float f; unsigned int i; } v; v.f = f;
    unsigned int r = v.i + 0x7fffu + ((v.i >> 16) & 1u);
    return (unsigned short)(r >> 16);
}

#define LOG2E  1.44269504f
#define LOG2E2 2.88539008f

// h = sigmoid(o) * tanh( sigmoid(i) * tanh(g) ), 3 exp + 2 rcp total.
// c = (e^{2g}-1)/((e^{2g}+1)(1+e^{-i})); tanh(c) via Pade(5,4) on |c|<1;
// h = c*N(c2) / (D(c2)*(1+e^{-o})). inf-safe: rcp(inf)=0.
__device__ __forceinline__ float lstm_h(float gi, float gg, float go) {
    gg = fminf(fmaxf(gg, -15.0f), 15.0f);
    float Eg = __builtin_amdgcn_exp2f(gg * LOG2E2);
    float Ei = __builtin_amdgcn_exp2f(-gi * LOG2E);
    float c  = (Eg - 1.0f) * __builtin_amdgcn_rcpf((Eg + 1.0f) * (1.0f + Ei));
    float Eo = __builtin_amdgcn_exp2f(-go * LOG2E);
    float c2 = c * c;
    float num = c * fmaf(c2, c2 + 105.0f, 945.0f);
    float den = fmaf(c2, fmaf(15.0f, c2, 420.0f), 945.0f);
    return num * __builtin_amdgcn_rcpf(den * (1.0f + Eo));
}

__device__ __forceinline__ void gload_lds16(const unsigned short* g, unsigned short* l) {
    __builtin_amdgcn_global_load_lds(
        (const __attribute__((address_space(1))) unsigned int*)g,
        (__attribute__((address_space(3))) unsigned int*)l,
        16, 0, 0);
}

// ---------------------------------------------------------------------------
// one-launch weight convert: 131072 float4 total (W1 32768 | W2 65536 | W3 32768)
// ---------------------------------------------------------------------------
__global__ __launch_bounds__(256) void k_convert3(
    const float* __restrict__ W1, const float* __restrict__ W2,
    const float* __restrict__ W3,
    unsigned short* __restrict__ d1, unsigned short* __restrict__ d2,
    unsigned short* __restrict__ d3)
{
    int i = blockIdx.x * 256 + threadIdx.x;
    const float* src; unsigned short* dst; int off;
    if (i < 32768)      { src = W1; dst = d1; off = i; }
    else if (i < 98304) { src = W2; dst = d2; off = i - 32768; }
    else                { src = W3; dst = d3; off = i - 98304; }
    float4 v = ((const float4*)src)[off];
    ushort4 o;
    o.x = f2bf(v.x); o.y = f2bf(v.y); o.z = f2bf(v.z); o.w = f2bf(v.w);
    ((ushort4*)dst)[off] = o;
}

// ---------------------------------------------------------------------------
// x (Bc, 128, 21) f32 -> xt (Bc*21, 128) bf16. One block per b.
// float4 loads (672/block), paired-uint stores (1344/block).
// ---------------------------------------------------------------------------
__global__ __launch_bounds__(256) void k_transpose(
    const float* __restrict__ x, unsigned short* __restrict__ xt)
{
    __shared__ unsigned short tile[128 * 22]; // [i][t], padded
    const int b = blockIdx.x, tid = threadIdx.x;
    const float4* xb4 = (const float4*)(x + (size_t)b * 2688);
    for (int j = tid; j < 672; j += 256) {
        float4 v = xb4[j];
        int e = j * 4;
        int ii = e / 21, tt = e - ii * 21;
        float vv[4] = {v.x, v.y, v.z, v.w};
#pragma unroll
        for (int k = 0; k < 4; ++k) {
            tile[ii * 22 + tt] = f2bf(vv[k]);
            if (++tt == 21) { tt = 0; ++ii; }
        }
    }
    __syncthreads();
    unsigned int* xtb = (unsigned int*)(xt + (size_t)b * 2688);
    for (int idx = tid; idx < 1344; idx += 256) {
        int t = idx >> 6, i2 = (idx & 63) * 2;
        unsigned int lo = tile[i2 * 22 + t];
        unsigned int hi = tile[(i2 + 1) * 22 + t];
        xtb[t * 64 + (idx & 63)] = lo | (hi << 16);
    }
}

// ---------------------------------------------------------------------------
// gates = A @ W^T + bias; h = lstm_h. A:(R,K) bf16, W:(4HG,K) bf16, f-gate dead.
// Block 128 rows x 64 cols x 3 gates; 4 waves (2x2); wave 64x32/gate.
// 2-phase pipeline, BK=32: double-buffered As/Ws (8+12 KB per buf = 40KB);
// per tile: STAGE(next) -> ds_read+MFMA(cur) -> barrier. Staging latency
// hides under compute; one barrier per tile (its implicit vmcnt(0) drain is
// cheap since loads were issued a full compute-phase earlier).
// LDS rows are 32 shorts = 4 x 16B slots; physical slot = logical ^ ((row>>1)&3)
// (inverse folded into the gload SOURCE address; LDS dest linear - rule 21).
// Read phases (16 lanes): 2 lanes/slot max = free (m136).
// launch_bounds(256,2): the no-spill allocation point (R4/R2 evidence).
// ---------------------------------------------------------------------------
template<int K, int HG>
__global__ __launch_bounds__(256, 2) void k_gemm_act(
    const unsigned short* __restrict__ A,
    const unsigned short* __restrict__ W,
    const float* __restrict__ bih,
    const float* __restrict__ bhh,
    unsigned short* __restrict__ Hout)
{
    __shared__ __align__(16) unsigned short As[2][128 * 32];
    __shared__ __align__(16) unsigned short Ws[2][192 * 32];

    const int tid  = threadIdx.x;
    const int wave = tid >> 6;
    const int lane = tid & 63;
    const int wm = wave >> 1;    // 0..1 -> 64 rows
    const int wn = wave & 1;     // 0..1 -> 32 cols
    const int r0 = blockIdx.x * 128;
    const int c0 = blockIdx.y * 64;
    const int csel = lane & 15;

    // ---- per-lane global source pointers (kk-invariant; swizzle folded in) ----
    // A: 8 chunks of 1KB (16 rows each); wave covers chunks 2w..2w+1.
    const unsigned short* aptr[2];
#pragma unroll
    for (int i = 0; i < 2; ++i) {
        int c = wave * 2 + i;
        int row = c * 16 + (lane >> 2);            // 0..127
        int lslot = (lane & 3) ^ ((row >> 1) & 3); // inverse swizzle on source
        aptr[i] = A + (size_t)(r0 + row) * K + lslot * 8;
    }
    // W: 12 chunks; wave covers chunks 3w..3w+2.
    const unsigned short* wptr[3];
#pragma unroll
    for (int i = 0; i < 3; ++i) {
        int c = wave * 3 + i;
        int row = c * 16 + (lane >> 2);            // 0..191
        int gate = row >> 6, n = row & 63;
        int gbase = (gate == 0) ? 0 : (gate + 1) * HG;   // i->0, g->2HG, o->3HG
        int lslot = (lane & 3) ^ ((row >> 1) & 3);
        wptr[i] = W + (size_t)(gbase + c0 + n) * K + lslot * 8;
    }

    // ---- bias -> registers ----
    float bias[3][2];
#pragma unroll
    for (int n = 0; n < 2; ++n) {
        int cloc = c0 + wn * 32 + n * 16 + csel;
        bias[0][n] = bih[cloc] + bhh[cloc];
        bias[1][n] = bih[2 * HG + cloc] + bhh[2 * HG + cloc];
        bias[2][n] = bih[3 * HG + cloc] + bhh[3 * HG + cloc];
    }

    f32x4 acc[3][4][2];
#pragma unroll
    for (int g = 0; g < 3; ++g)
#pragma unroll
        for (int m = 0; m < 4; ++m)
#pragma unroll
            for (int n = 0; n < 2; ++n)
                acc[g][m][n] = (f32x4){0.f, 0.f, 0.f, 0.f};

    // ---- prologue: stage tile 0 into buffer 0 ----
#pragma unroll
    for (int i = 0; i < 2; ++i)
        gload_lds16(aptr[i], &As[0][(wave * 2 + i) * 512]);
#pragma unroll
    for (int i = 0; i < 3; ++i)
        gload_lds16(wptr[i], &Ws[0][(wave * 3 + i) * 512]);
    __syncthreads();

    int cur = 0;
#pragma unroll
    for (int kk = 0; kk < K; kk += 32) {
        // ---- stage NEXT tile into other buffer (latency hides under MFMA) ----
        if (kk + 32 < K) {
#pragma unroll
            for (int i = 0; i < 2; ++i)
                gload_lds16(aptr[i] + kk + 32, &As[cur ^ 1][(wave * 2 + i) * 512]);
#pragma unroll
            for (int i = 0; i < 3; ++i)
                gload_lds16(wptr[i] + kk + 32, &Ws[cur ^ 1][(wave * 3 + i) * 512]);
        }

        // ---- ds_read + MFMA on current buffer ----
        {
            bf16x8 af[4];
            bf16x8 bfr[3][2];
            const int q = lane >> 4;               // logical 16B slot 0..3
#pragma unroll
            for (int m = 0; m < 4; ++m) {
                int row = wm * 64 + m * 16 + csel;
                int p = q ^ ((row >> 1) & 3);
                af[m] = *(const bf16x8*)&As[cur][row * 32 + p * 8];
            }
#pragma unroll
            for (int g = 0; g < 3; ++g)
#pragma unroll
                for (int n = 0; n < 2; ++n) {
                    int row = g * 64 + wn * 32 + n * 16 + csel;
                    int p = q ^ ((row >> 1) & 3);
                    bfr[g][n] = *(const bf16x8*)&Ws[cur][row * 32 + p * 8];
                }
#pragma unroll
            for (int g = 0; g < 3; ++g)
#pragma unroll
                for (int m = 0; m < 4; ++m)
#pragma unroll
                    for (int n = 0; n < 2; ++n)
                        acc[g][m][n] = __builtin_amdgcn_mfma_f32_16x16x32_bf16(
                            af[m], bfr[g][n], acc[g][m][n], 0, 0, 0);
        }
        __syncthreads();   // next buffer fully staged; current fully consumed
        cur ^= 1;
    }

    // epilogue: C/D layout col = lane&15, row = (lane>>4)*4 + reg
    const int quad = lane >> 4;
#pragma unroll
    for (int m = 0; m < 4; ++m) {
#pragma unroll
        for (int n = 0; n < 2; ++n) {
            int cloc = wn * 32 + n * 16 + csel;
            f32x4 vi = acc[0][m][n], vg = acc[1][m][n], vo = acc[2][m][n];
#pragma unroll
            for (int r = 0; r < 4; ++r) {
                int row = r0 + wm * 64 + m * 16 + quad * 4 + r;
                float h = lstm_h(vi[r] + bias[0][n], vg[r] + bias[1][n],
                                 vo[r] + bias[2][n]);
                Hout[(size_t)row * HG + c0 + cloc] = f2bf(h);
            }
        }
    }
}

// ---------------------------------------------------------------------------
// fc1 + fc2 fused. h3 bf16; fc weights/biases f32; out f32. 8 batches/block.
// ---------------------------------------------------------------------------
#define FSTR 169
__global__ __launch_bounds__(256) void k_final(
    const unsigned short* __restrict__ h3,
    const float* __restrict__ fc1w,
    const float* __restrict__ fc1b,
    const float* __restrict__ fc2w,
    const float* __restrict__ fc2b,
    float* __restrict__ out)
{
    __shared__ unsigned short ht[128 * FSTR];  // [c][task], task = bloc*21+t
    __shared__ float fwl[128];
    __shared__ float yl[168];
    __shared__ float f2l[441];
    __shared__ float f2bl[21];

    const int tid = threadIdx.x;
    const int b0 = blockIdx.x * 8;

    if (tid < 128) fwl[tid] = fc1w[tid];
    for (int i = tid; i < 441; i += 256) f2l[i] = fc2w[i];
    if (tid < 21) f2bl[tid] = fc2b[tid];

    const unsigned int* hsrc = (const unsigned int*)(h3 + (size_t)b0 * 2688);
    for (int gi = tid; gi < 10752; gi += 256) {
        unsigned int v = hsrc[gi];
        int e = gi * 2;
        int task = e >> 7;
        int c = e & 127;
        ht[c * FSTR + task] = (unsigned short)(v & 0xffffu);
        ht[(c + 1) * FSTR + task] = (unsigned short)(v >> 16);
    }
    __syncthreads();

    const float f1b = fc1b[0];
    if (tid < 168) {
        float s = f1b;
#pragma unroll 8
        for (int c = 0; c < 128; ++c)
            s += fwl[c] * bf2f(ht[c * FSTR + tid]);
        yl[tid] = s;
    }
    __syncthreads();
    if (tid < 168) {
        int bloc = tid / 21;
        int tp = tid - bloc * 21;
        float s = f2bl[tp];
#pragma unroll
        for (int t = 0; t < 21; ++t)
            s += yl[bloc * 21 + t] * f2l[tp * 21 + t];
        out[(size_t)(b0 + bloc) * 21 + tp] = s;
    }
}

// ---------------------------------------------------------------------------
extern "C" void kernel_launch(void* const* d_in, const int* in_sizes, int n_in,
                              void* d_out, int out_size, void* d_ws, size_t ws_size,
                              hipStream_t stream)
{
    const float* x    = (const float*)d_in[0];
    const float* W1   = (const float*)d_in[1];
    const float* b1i  = (const float*)d_in[2];
    const float* b1h  = (const float*)d_in[3];
    const float* W2   = (const float*)d_in[4];
    const float* b2i  = (const float*)d_in[5];
    const float* b2h  = (const float*)d_in[6];
    const float* W3   = (const float*)d_in[7];
    const float* b3i  = (const float*)d_in[8];
    const float* b3h  = (const float*)d_in[9];
    const float* fc1w = (const float*)d_in[10];
    const float* fc1b = (const float*)d_in[11];
    const float* fc2w = (const float*)d_in[12];
    const float* fc2b = (const float*)d_in[13];
    float* out = (float*)d_out;

    unsigned short* Wc1 = (unsigned short*)d_ws;
    unsigned short* Wc2 = Wc1 + 131072;
    unsigned short* Wc3 = Wc2 + 262144;
    unsigned short* buf = Wc3 + 131072;          // 1,048,576 B in

    int C = 1;
    while (C < 64 && 1048576 + (size_t)(M_ROWS / C) * 1536 > ws_size) C <<= 1;
    const int R  = M_ROWS / C;
    const int Bc = BATCH / C;

    unsigned short* xt = buf;
    unsigned short* h1 = xt + (size_t)R * 128;
    unsigned short* h2 = h1 + (size_t)R * 256;
    unsigned short* h3 = h2 + (size_t)R * 256;

    k_convert3<<<512, 256, 0, stream>>>(W1, W2, W3, Wc1, Wc2, Wc3);

    for (int c = 0; c < C; ++c) {
        const float* xc = x + (size_t)c * Bc * 2688;
        k_transpose<<<Bc, 256, 0, stream>>>(xc, xt);
        k_gemm_act<128, 256><<<dim3(R / 128, 4), 256, 0, stream>>>(xt, Wc1, b1i, b1h, h1);
        k_gemm_act<256, 256><<<dim3(R / 128, 4), 256, 0, stream>>>(h1, Wc2, b2i, b2h, h2);
        k_gemm_act<256, 128><<<dim3(R / 128, 2), 256, 0, stream>>>(h2, Wc3, b3i, b3h, h3);
        k_final<<<Bc / 8, 256, 0, stream>>>(h3, fc1w, fc1b, fc2w, fc2b,
                                            out + (size_t)c * Bc * 21);
    }
}

// Round 14
// 403.971 us; speedup vs baseline: 1.0295x; 1.0295x over previous
//
#include <hip/hip_runtime.h>
#include <hip/hip_bf16.h>
#include <stdint.h>

// ---------------------------------------------------------------------------
// LSTM2: 3 stacked single-step LSTM cells (h0=c0=0 => f-gate dead) + fc1+fc2.
// B=8192, I=128, T=21 -> M = 172032 rows.
// R1: XOR-swizzle LDS (bank conflicts -> 0, verified).
// R2: global_load_lds width=16 staging.
// R3: row-fastest grid; cheap activation (8 -> 5 trans ops/h).
// R4: FAILED - (256,4): acc spilled (WRITE 608MB). VGPR_Count excludes ~96
//     AGPR acc; total ~200/wave -> 2 waves/SIMD is the no-spill ceiling.
// R5: BEST 406us. L2-gemm 112us, FETCH=174MB = 2x A (L3 thrash across the
//     4 col-passes; 88MB reuse distance).
// R8: FAILED - BK=32 dbuf pipeline: 2x barriers, drain still uncovered
//     (125.5us, -12%). m99/m100 confirmed: dbuf neutral-to-neg here.
//     BUT transpose-f4/convert3 saved ~17us -> kept.
// R11: R5 gemm structure restored + segment-blocked dispatch remap:
//     process 336 row-tiles x all col-passes before advancing. A-panel
//     reuse distance 88MB -> 22MB (L3-resident; 336%8==0 -> same XCD
//     re-reads its own rows from its own L2). Pure index remap, no
//     structural change.
// ---------------------------------------------------------------------------

typedef __attribute__((ext_vector_type(8))) short bf16x8;
typedef __attribute__((ext_vector_type(4))) float f32x4;

#define M_ROWS 172032
#define BATCH  8192

__device__ __forceinline__ float bf2f(unsigned short u) {
    union { unsigned int i; float f; } v; v.i = ((unsigned int)u) << 16; return v.f;
}
__device__ __forceinline__ unsigned short f2bf(float f) {
    union { float f; unsigned int i; } v; v.f = f;
    unsigned int r = v.i + 0x7fffu + ((v.i >> 16) & 1u);
    return (unsigned short)(r >> 16);
}

#define LOG2E  1.44269504f
#define LOG2E2 2.88539008f

// h = sigmoid(o) * tanh( sigmoid(i) * tanh(g) ), 3 exp + 2 rcp total.
// c = (e^{2g}-1)/((e^{2g}+1)(1+e^{-i})); tanh(c) via Pade(5,4) on |c|<1;
// h = c*N(c2) / (D(c2)*(1+e^{-o})). inf-safe: rcp(inf)=0.
__device__ __forceinline__ float lstm_h(float gi, float gg, float go) {
    gg = fminf(fmaxf(gg, -15.0f), 15.0f);
    float Eg = __builtin_amdgcn_exp2f(gg * LOG2E2);
    float Ei = __builtin_amdgcn_exp2f(-gi * LOG2E);
    float c  = (Eg - 1.0f) * __builtin_amdgcn_rcpf((Eg + 1.0f) * (1.0f + Ei));
    float Eo = __builtin_amdgcn_exp2f(-go * LOG2E);
    float c2 = c * c;
    float num = c * fmaf(c2, c2 + 105.0f, 945.0f);
    float den = fmaf(c2, fmaf(15.0f, c2, 420.0f), 945.0f);
    return num * __builtin_amdgcn_rcpf(den * (1.0f + Eo));
}

__device__ __forceinline__ void gload_lds16(const unsigned short* g, unsigned short* l) {
    __builtin_amdgcn_global_load_lds(
        (const __attribute__((address_space(1))) unsigned int*)g,
        (__attribute__((address_space(3))) unsigned int*)l,
        16, 0, 0);
}

// ---------------------------------------------------------------------------
// one-launch weight convert: 131072 float4 total (W1 32768 | W2 65536 | W3 32768)
// ---------------------------------------------------------------------------
__global__ __launch_bounds__(256) void k_convert3(
    const float* __restrict__ W1, const float* __restrict__ W2,
    const float* __restrict__ W3,
    unsigned short* __restrict__ d1, unsigned short* __restrict__ d2,
    unsigned short* __restrict__ d3)
{
    int i = blockIdx.x * 256 + threadIdx.x;
    const float* src; unsigned short* dst; int off;
    if (i < 32768)      { src = W1; dst = d1; off = i; }
    else if (i < 98304) { src = W2; dst = d2; off = i - 32768; }
    else                { src = W3; dst = d3; off = i - 98304; }
    float4 v = ((const float4*)src)[off];
    ushort4 o;
    o.x = f2bf(v.x); o.y = f2bf(v.y); o.z = f2bf(v.z); o.w = f2bf(v.w);
    ((ushort4*)dst)[off] = o;
}

// ---------------------------------------------------------------------------
// x (Bc, 128, 21) f32 -> xt (Bc*21, 128) bf16. One block per b.
// float4 loads (672/block), paired-uint stores (1344/block).
// ---------------------------------------------------------------------------
__global__ __launch_bounds__(256) void k_transpose(
    const float* __restrict__ x, unsigned short* __restrict__ xt)
{
    __shared__ unsigned short tile[128 * 22]; // [i][t], padded
    const int b = blockIdx.x, tid = threadIdx.x;
    const float4* xb4 = (const float4*)(x + (size_t)b * 2688);
    for (int j = tid; j < 672; j += 256) {
        float4 v = xb4[j];
        int e = j * 4;
        int ii = e / 21, tt = e - ii * 21;
        float vv[4] = {v.x, v.y, v.z, v.w};
#pragma unroll
        for (int k = 0; k < 4; ++k) {
            tile[ii * 22 + tt] = f2bf(vv[k]);
            if (++tt == 21) { tt = 0; ++ii; }
        }
    }
    __syncthreads();
    unsigned int* xtb = (unsigned int*)(xt + (size_t)b * 2688);
    for (int idx = tid; idx < 1344; idx += 256) {
        int t = idx >> 6, i2 = (idx & 63) * 2;
        unsigned int lo = tile[i2 * 22 + t];
        unsigned int hi = tile[(i2 + 1) * 22 + t];
        xtb[t * 64 + (idx & 63)] = lo | (hi << 16);
    }
}

// ---------------------------------------------------------------------------
// gates = A @ W^T + bias; h = lstm_h. A:(R,K) bf16, W:(4HG,K) bf16, f-gate dead.
// Block 128 rows x 64 cols x 3 gates; 4 waves (2x2); wave 64x32/gate.
// R5 structure: BK=64 single LDS buffer, gload_lds(16B) staging, 2 barriers
// per kk, 8-slot XOR swizzle folded into the global SOURCE address (LDS dest
// linear - rule 21); fragment reads apply the same XOR (conflicts=0 verified).
// launch_bounds(256,2): the no-spill point (acc ~96 AGPR + ~104 VGPR = 2/SIMD).
// Segment-blocked dispatch: lin -> (seg, col, rowInSeg) with 336-row-tile
// segments, so the A panel re-read across col-passes has 22MB reuse distance
// (L3-resident; same-XCD L2 likely since 336%8==0). Identity when
// gridDim.x % 336 != 0 (small chunks).
// ---------------------------------------------------------------------------
template<int K, int HG>
__global__ __launch_bounds__(256, 2) void k_gemm_act(
    const unsigned short* __restrict__ A,
    const unsigned short* __restrict__ W,
    const float* __restrict__ bih,
    const float* __restrict__ bhh,
    unsigned short* __restrict__ Hout)
{
    __shared__ __align__(16) unsigned short As[128 * 64];  // [row][k] src-swizzled
    __shared__ __align__(16) unsigned short Ws[192 * 64];  // [gate*64+n][k] src-swizzled

    const int tid  = threadIdx.x;
    const int wave = tid >> 6;
    const int lane = tid & 63;
    const int wm = wave >> 1;    // 0..1 -> 64 rows
    const int wn = wave & 1;     // 0..1 -> 32 cols
    const int csel = lane & 15;

    // ---- segment-blocked dispatch remap (pure bijection) ----
    int bx = blockIdx.x, by = blockIdx.y;
    if ((gridDim.x % 336) == 0) {
        int ny = gridDim.y;
        int lin = by * gridDim.x + bx;        // dispatch order (x fastest)
        int segblocks = 336 * ny;
        int seg = lin / segblocks;
        int rem = lin - seg * segblocks;
        by = rem / 336;
        bx = seg * 336 + (rem - by * 336);
    }
    const int r0 = bx * 128;
    const int c0 = by * 64;

    // ---- per-lane global source pointers (kk-invariant; swizzle folded in) ----
    const unsigned short* aptr[4];
#pragma unroll
    for (int i = 0; i < 4; ++i) {
        int q16 = (wave * 4 + i) * 64 + lane;      // 16B-unit index in A tile
        int row = q16 >> 3, pslot = q16 & 7;
        int lslot = pslot ^ (row & 7);             // inverse swizzle on source
        aptr[i] = A + (size_t)(r0 + row) * K + lslot * 8;
    }
    const unsigned short* wptr[6];
#pragma unroll
    for (int i = 0; i < 6; ++i) {
        int q16 = (wave * 6 + i) * 64 + lane;      // 16B-unit index in W tile
        int lrow = q16 >> 3, pslot = q16 & 7;
        int lslot = pslot ^ (lrow & 7);
        int gate = lrow >> 6, n = lrow & 63;
        int gbase = (gate == 0) ? 0 : (gate + 1) * HG;   // i->0, g->2HG, o->3HG
        wptr[i] = W + (size_t)(gbase + c0 + n) * K + lslot * 8;
    }

    // ---- bias -> registers (latency overlaps first staging) ----
    float bias[3][2];
#pragma unroll
    for (int n = 0; n < 2; ++n) {
        int cloc = c0 + wn * 32 + n * 16 + csel;
        bias[0][n] = bih[cloc] + bhh[cloc];
        bias[1][n] = bih[2 * HG + cloc] + bhh[2 * HG + cloc];
        bias[2][n] = bih[3 * HG + cloc] + bhh[3 * HG + cloc];
    }

    f32x4 acc[3][4][2];
#pragma unroll
    for (int g = 0; g < 3; ++g)
#pragma unroll
        for (int m = 0; m < 4; ++m)
#pragma unroll
            for (int n = 0; n < 2; ++n)
                acc[g][m][n] = (f32x4){0.f, 0.f, 0.f, 0.f};

#pragma unroll
    for (int kk = 0; kk < K; kk += 64) {
        if (kk) __syncthreads();               // prev tile fully consumed
        // ---- async stage tile kk (no VGPR round-trip) ----
#pragma unroll
        for (int i = 0; i < 4; ++i)
            gload_lds16(aptr[i] + kk, &As[(wave * 4 + i) * 512]);
#pragma unroll
        for (int i = 0; i < 6; ++i)
            gload_lds16(wptr[i] + kk, &Ws[(wave * 6 + i) * 512]);
        __syncthreads();                       // vmcnt(0) drain + visibility

        // ---- MFMA on the staged 64-k tile ----
#pragma unroll
        for (int ks = 0; ks < 64; ks += 32) {
            bf16x8 af[4];
            bf16x8 bfr[3][2];
            const int rsel = lane & 15;
            const int slot = (ks >> 3) | (lane >> 4);    // logical 16B slot 0..7
            const int soff = (slot ^ (rsel & 7)) * 8;    // swizzled short offset
#pragma unroll
            for (int m = 0; m < 4; ++m)
                af[m] = *(const bf16x8*)&As[(wm * 64 + m * 16 + rsel) * 64 + soff];
#pragma unroll
            for (int g = 0; g < 3; ++g)
#pragma unroll
                for (int n = 0; n < 2; ++n)
                    bfr[g][n] = *(const bf16x8*)&Ws[(g * 64 + wn * 32 + n * 16 + rsel) * 64 + soff];
#pragma unroll
            for (int g = 0; g < 3; ++g)
#pragma unroll
                for (int m = 0; m < 4; ++m)
#pragma unroll
                    for (int n = 0; n < 2; ++n)
                        acc[g][m][n] = __builtin_amdgcn_mfma_f32_16x16x32_bf16(
                            af[m], bfr[g][n], acc[g][m][n], 0, 0, 0);
        }
    }

    // epilogue: C/D layout col = lane&15, row = (lane>>4)*4 + reg
    const int quad = lane >> 4;
#pragma unroll
    for (int m = 0; m < 4; ++m) {
#pragma unroll
        for (int n = 0; n < 2; ++n) {
            int cloc = wn * 32 + n * 16 + csel;
            f32x4 vi = acc[0][m][n], vg = acc[1][m][n], vo = acc[2][m][n];
#pragma unroll
            for (int r = 0; r < 4; ++r) {
                int row = r0 + wm * 64 + m * 16 + quad * 4 + r;
                float h = lstm_h(vi[r] + bias[0][n], vg[r] + bias[1][n],
                                 vo[r] + bias[2][n]);
                Hout[(size_t)row * HG + c0 + cloc] = f2bf(h);
            }
        }
    }
}

// ---------------------------------------------------------------------------
// fc1 + fc2 fused. h3 bf16; fc weights/biases f32; out f32. 8 batches/block.
// ---------------------------------------------------------------------------
#define FSTR 169
__global__ __launch_bounds__(256) void k_final(
    const unsigned short* __restrict__ h3,
    const float* __restrict__ fc1w,
    const float* __restrict__ fc1b,
    const float* __restrict__ fc2w,
    const float* __restrict__ fc2b,
    float* __restrict__ out)
{
    __shared__ unsigned short ht[128 * FSTR];  // [c][task], task = bloc*21+t
    __shared__ float fwl[128];
    __shared__ float yl[168];
    __shared__ float f2l[441];
    __shared__ float f2bl[21];

    const int tid = threadIdx.x;
    const int b0 = blockIdx.x * 8;

    if (tid < 128) fwl[tid] = fc1w[tid];
    for (int i = tid; i < 441; i += 256) f2l[i] = fc2w[i];
    if (tid < 21) f2bl[tid] = fc2b[tid];

    const unsigned int* hsrc = (const unsigned int*)(h3 + (size_t)b0 * 2688);
    for (int gi = tid; gi < 10752; gi += 256) {
        unsigned int v = hsrc[gi];
        int e = gi * 2;
        int task = e >> 7;
        int c = e & 127;
        ht[c * FSTR + task] = (unsigned short)(v & 0xffffu);
        ht[(c + 1) * FSTR + task] = (unsigned short)(v >> 16);
    }
    __syncthreads();

    const float f1b = fc1b[0];
    if (tid < 168) {
        float s = f1b;
#pragma unroll 8
        for (int c = 0; c < 128; ++c)
            s += fwl[c] * bf2f(ht[c * FSTR + tid]);
        yl[tid] = s;
    }
    __syncthreads();
    if (tid < 168) {
        int bloc = tid / 21;
        int tp = tid - bloc * 21;
        float s = f2bl[tp];
#pragma unroll
        for (int t = 0; t < 21; ++t)
            s += yl[bloc * 21 + t] * f2l[tp * 21 + t];
        out[(size_t)(b0 + bloc) * 21 + tp] = s;
    }
}

// ---------------------------------------------------------------------------
extern "C" void kernel_launch(void* const* d_in, const int* in_sizes, int n_in,
                              void* d_out, int out_size, void* d_ws, size_t ws_size,
                              hipStream_t stream)
{
    const float* x    = (const float*)d_in[0];
    const float* W1   = (const float*)d_in[1];
    const float* b1i  = (const float*)d_in[2];
    const float* b1h  = (const float*)d_in[3];
    const float* W2   = (const float*)d_in[4];
    const float* b2i  = (const float*)d_in[5];
    const float* b2h  = (const float*)d_in[6];
    const float* W3   = (const float*)d_in[7];
    const float* b3i  = (const float*)d_in[8];
    const float* b3h  = (const float*)d_in[9];
    const float* fc1w = (const float*)d_in[10];
    const float* fc1b = (const float*)d_in[11];
    const float* fc2w = (const float*)d_in[12];
    const float* fc2b = (const float*)d_in[13];
    float* out = (float*)d_out;

    unsigned short* Wc1 = (unsigned short*)d_ws;
    unsigned short* Wc2 = Wc1 + 131072;
    unsigned short* Wc3 = Wc2 + 262144;
    unsigned short* buf = Wc3 + 131072;          // 1,048,576 B in

    int C = 1;
    while (C < 64 && 1048576 + (size_t)(M_ROWS / C) * 1536 > ws_size) C <<= 1;
    const int R  = M_ROWS / C;
    const int Bc = BATCH / C;

    unsigned short* xt = buf;
    unsigned short* h1 = xt + (size_t)R * 128;
    unsigned short* h2 = h1 + (size_t)R * 256;
    unsigned short* h3 = h2 + (size_t)R * 256;

    k_convert3<<<512, 256, 0, stream>>>(W1, W2, W3, Wc1, Wc2, Wc3);

    for (int c = 0; c < C; ++c) {
        const float* xc = x + (size_t)c * Bc * 2688;
        k_transpose<<<Bc, 256, 0, stream>>>(xc, xt);
        k_gemm_act<128, 256><<<dim3(R / 128, 4), 256, 0, stream>>>(xt, Wc1, b1i, b1h, h1);
        k_gemm_act<256, 256><<<dim3(R / 128, 4), 256, 0, stream>>>(h1, Wc2, b2i, b2h, h2);
        k_gemm_act<256, 128><<<dim3(R / 128, 2), 256, 0, stream>>>(h2, Wc3, b3i, b3h, h3);
        k_final<<<Bc / 8, 256, 0, stream>>>(h3, fc1w, fc1b, fc2w, fc2b,
                                            out + (size_t)c * Bc * 21);
    }
}